// Round 5
// baseline (565.955 us; speedup 1.0000x reference)
//
#include <hip/hip_runtime.h>
#include <hip/hip_bf16.h>
#include <math.h>

#define L 1024
typedef __hip_bfloat16 bf;

__device__ __forceinline__ float b2f(bf v) { return __bfloat162float(v); }
__device__ __forceinline__ bf f2b(float v) { return __float2bfloat16(v); }

// ---- k_front: 1x1 conv + BN + exact GELU + in_proj -> xm(bf16), z(bf16) ----
__global__ __launch_bounds__(256) void k_front(
    const float* __restrict__ x, const float* __restrict__ conv_w,
    const float* __restrict__ conv_b, const float* __restrict__ gamma,
    const float* __restrict__ beta, const float* __restrict__ mean,
    const float* __restrict__ var, const float* __restrict__ ipw,
    bf* __restrict__ xm, bf* __restrict__ z) {
  int tid = blockIdx.x * 256 + threadIdx.x;   // 65536 = (b,l)
  int l = tid & (L - 1);
  int b = tid >> 10;
  const float* xp = x + (size_t)b * 65536 + l;
  float xv[64];
#pragma unroll
  for (int c = 0; c < 64; ++c) xv[c] = xp[c * L];
  float h[32];
#pragma unroll
  for (int d = 0; d < 32; ++d) {
    float acc = conv_b[d];
#pragma unroll
    for (int c = 0; c < 64; ++c) acc = fmaf(xv[c], conv_w[d * 64 + c], acc);
    float sc = gamma[d] * rsqrtf(var[d] + 1e-5f);
    acc = (acc - mean[d]) * sc + beta[d];
    h[d] = 0.5f * acc * (1.0f + erff(acc * 0.70710678118654752f));
  }
  for (int j = 0; j < 64; ++j) {
    float a0 = 0.f, a1 = 0.f;
#pragma unroll
    for (int d = 0; d < 32; ++d) {
      a0 = fmaf(h[d], ipw[j * 32 + d], a0);
      a1 = fmaf(h[d], ipw[(j + 64) * 32 + d], a1);
    }
    xm[(size_t)b * 65536 + j * L + l] = f2b(a0);
    z [(size_t)b * 65536 + j * L + l] = f2b(a1);
  }
}

// ---- k_mid: depthwise conv1d + SiLU + x_proj + dt(softplus) ----
__global__ __launch_bounds__(256) void k_mid(
    const bf* __restrict__ xm, const float* __restrict__ c1w,
    const float* __restrict__ c1b, const float* __restrict__ xpw,
    const float* __restrict__ dtw, const float* __restrict__ dtbp,
    bf* __restrict__ u, bf* __restrict__ dt_o,
    bf* __restrict__ Bt, bf* __restrict__ Ct) {
  int tid = blockIdx.x * 256 + threadIdx.x;   // (b,l)
  int l = tid & (L - 1);
  int b = tid >> 10;
  float um[64];
#pragma unroll
  for (int d = 0; d < 64; ++d) {
    float acc = c1b[d];
#pragma unroll
    for (int k = 0; k < 4; ++k) {
      int ls = l - 3 + k;
      float v = (ls >= 0) ? b2f(xm[(size_t)b * 65536 + d * L + ls]) : 0.f;
      acc = fmaf(c1w[d * 4 + k], v, acc);
    }
    float s = acc / (1.f + __expf(-acc));
    um[d] = s;
    u[(size_t)b * 65536 + d * L + l] = f2b(s);
  }
  float xd[34];
  for (int k = 0; k < 34; ++k) {
    float acc = 0.f;
#pragma unroll
    for (int d = 0; d < 64; ++d) acc = fmaf(um[d], xpw[k * 64 + d], acc);
    xd[k] = acc;
  }
#pragma unroll
  for (int d = 0; d < 64; ++d) {
    float raw = fmaf(xd[0], dtw[d * 2], fmaf(xd[1], dtw[d * 2 + 1], dtbp[d]));
    float sp = fmaxf(raw, 0.f) + log1pf(__expf(-fabsf(raw)));
    dt_o[(size_t)b * 65536 + d * L + l] = f2b(sp);
  }
#pragma unroll
  for (int n2 = 0; n2 < 16; ++n2) {
    Bt[(size_t)b * 16384 + l * 16 + n2] = f2b(xd[2 + n2]);
    Ct[(size_t)b * 16384 + l * 16 + n2] = f2b(xd[18 + n2]);
  }
}

// ---- k_scan: one lane per (b,d,n); sequential over l ----
__global__ __launch_bounds__(256) void k_scan(
    const bf* __restrict__ u, const bf* __restrict__ dt,
    const bf* __restrict__ Bt, const bf* __restrict__ Ct,
    const float* __restrict__ A_log, bf* __restrict__ ys) {
  int tid = blockIdx.x * 256 + threadIdx.x;   // 65536 = (b,d,n)
  int n = tid & 15;
  int d = (tid >> 4) & 63;
  int b = tid >> 10;
  float A = -__expf(A_log[d * 16 + n]);
  const bf* up = u + (size_t)b * 65536 + d * L;
  const bf* dtp = dt + (size_t)b * 65536 + d * L;
  const bf* Bp = Bt + (size_t)b * 16384;
  const bf* Cp = Ct + (size_t)b * 16384;
  bf* yp = ys + (size_t)b * 65536 + d * L;
  float hst = 0.f;
#pragma unroll 4
  for (int l = 0; l < L; ++l) {
    float dtv = b2f(dtp[l]);
    float uv = b2f(up[l]);
    float Bv = b2f(Bp[l * 16 + n]);
    float Cv = b2f(Cp[l * 16 + n]);
    float a = __expf(dtv * A);
    hst = fmaf(a, hst, dtv * uv * Bv);
    float p = hst * Cv;
    p += __shfl_xor(p, 1);
    p += __shfl_xor(p, 2);
    p += __shfl_xor(p, 4);
    p += __shfl_xor(p, 8);
    if (n == 0) yp[l] = f2b(p);
  }
}

// ---- k_tail: gate + out_proj + mean-pool + fc, one block per batch ----
// Output dtype: FLOAT32 (reference output is f32).
__global__ __launch_bounds__(256) void k_tail(
    const bf* __restrict__ ys, const bf* __restrict__ u,
    const bf* __restrict__ z, const float* __restrict__ Dp,
    const float* __restrict__ opw, const float* __restrict__ fcw,
    const float* __restrict__ fcb, float* __restrict__ out) {
  __shared__ float red[256 * 32];   // 32 KB
  __shared__ float pooled[32];
  int b = blockIdx.x;
  int t = threadIdx.x;
  float o[32];
#pragma unroll
  for (int j = 0; j < 32; ++j) o[j] = 0.f;
  for (int li = 0; li < 4; ++li) {
    int l = t + li * 256;
    for (int d = 0; d < 64; ++d) {
      size_t idx = (size_t)b * 65536 + (size_t)d * L + l;
      float yv = b2f(ys[idx]);
      float uv = b2f(u[idx]);
      float zv = b2f(z[idx]);
      float yd = fmaf(uv, Dp[d], yv) * (zv / (1.f + __expf(-zv)));
#pragma unroll
      for (int j = 0; j < 32; ++j) o[j] = fmaf(yd, opw[j * 64 + d], o[j]);
    }
  }
#pragma unroll
  for (int j = 0; j < 32; ++j) red[t * 32 + j] = o[j];
  __syncthreads();
  if (t < 32) {
    float s = 0.f;
    for (int tt = 0; tt < 256; ++tt) s += red[tt * 32 + t];
    pooled[t] = s * (1.f / 1024.f);
  }
  __syncthreads();
  if (t < 128) {
    float acc = fcb[t];
#pragma unroll
    for (int d = 0; d < 32; ++d) acc = fmaf(pooled[d], fcw[t * 32 + d], acc);
    out[b * 128 + t] = acc;   // f32 write
  }
}

extern "C" void kernel_launch(void* const* d_in, const int* in_sizes, int n_in,
                              void* d_out, int out_size, void* d_ws, size_t ws_size,
                              hipStream_t stream) {
  const float* x      = (const float*)d_in[0];
  const float* conv_w = (const float*)d_in[1];
  const float* conv_b = (const float*)d_in[2];
  const float* bn_g   = (const float*)d_in[3];
  const float* bn_b   = (const float*)d_in[4];
  const float* bn_m   = (const float*)d_in[5];
  const float* bn_v   = (const float*)d_in[6];
  const float* ipw    = (const float*)d_in[7];
  const float* c1w    = (const float*)d_in[8];
  const float* c1b    = (const float*)d_in[9];
  const float* xpw    = (const float*)d_in[10];
  const float* dtw    = (const float*)d_in[11];
  const float* dtbp   = (const float*)d_in[12];
  const float* A_log  = (const float*)d_in[13];
  const float* Dp     = (const float*)d_in[14];
  const float* opw    = (const float*)d_in[15];
  const float* fcw    = (const float*)d_in[16];
  const float* fcb    = (const float*)d_in[17];

  char* ws = (char*)d_ws;
  bf* xmb = (bf*)(ws + 0);               // 8 MB
  bf* zb  = (bf*)(ws + 8388608);         // 8 MB
  bf* ub  = (bf*)(ws + 16777216);        // 8 MB
  bf* dtb = (bf*)(ws + 25165824);        // 8 MB
  bf* Btb = (bf*)(ws + 33554432);        // 2 MB
  bf* Ctb = (bf*)(ws + 35651584);        // 2 MB
  bf* ysb = (bf*)(ws + 37748736);        // 8 MB

  hipLaunchKernelGGL(k_front, dim3(256), dim3(256), 0, stream,
                     x, conv_w, conv_b, bn_g, bn_b, bn_m, bn_v, ipw, xmb, zb);
  hipLaunchKernelGGL(k_mid, dim3(256), dim3(256), 0, stream,
                     xmb, c1w, c1b, xpw, dtw, dtbp, ub, dtb, Btb, Ctb);
  hipLaunchKernelGGL(k_scan, dim3(256), dim3(256), 0, stream,
                     ub, dtb, Btb, Ctb, A_log, ysb);
  hipLaunchKernelGGL(k_tail, dim3(64), dim3(256), 0, stream,
                     ysb, ub, zb, Dp, opw, fcw, fcb, (float*)d_out);
}

// Round 6
// 375.841 us; speedup vs baseline: 1.5058x; 1.5058x over previous
//
#include <hip/hip_runtime.h>
#include <hip/hip_bf16.h>
#include <math.h>

#define L 1024
typedef __hip_bfloat16 bf;
typedef __attribute__((ext_vector_type(8))) short short8;

__device__ __forceinline__ float b2f(bf v) { return __bfloat162float(v); }
__device__ __forceinline__ bf f2b(float v) { return __float2bfloat16(v); }
__device__ __forceinline__ float bits2f(short s) {
  union { unsigned u; float f; } cv; cv.u = ((unsigned)(unsigned short)s) << 16; return cv.f;
}

// ---- k_front: 1x1 conv + BN + exact GELU + in_proj -> xm(bf16), z(bf16) ----
__global__ __launch_bounds__(256) void k_front(
    const float* __restrict__ x, const float* __restrict__ conv_w,
    const float* __restrict__ conv_b, const float* __restrict__ gamma,
    const float* __restrict__ beta, const float* __restrict__ mean,
    const float* __restrict__ var, const float* __restrict__ ipw,
    bf* __restrict__ xm, bf* __restrict__ z) {
  int tid = blockIdx.x * 256 + threadIdx.x;   // 65536 = (b,l)
  int l = tid & (L - 1);
  int b = tid >> 10;
  const float* xp = x + (size_t)b * 65536 + l;
  float xv[64];
#pragma unroll
  for (int c = 0; c < 64; ++c) xv[c] = xp[c * L];
  float h[32];
#pragma unroll
  for (int d = 0; d < 32; ++d) {
    float acc = conv_b[d];
#pragma unroll
    for (int c = 0; c < 64; ++c) acc = fmaf(xv[c], conv_w[d * 64 + c], acc);
    float sc = gamma[d] * rsqrtf(var[d] + 1e-5f);
    acc = (acc - mean[d]) * sc + beta[d];
    h[d] = 0.5f * acc * (1.0f + erff(acc * 0.70710678118654752f));
  }
  for (int j = 0; j < 64; ++j) {
    float a0 = 0.f, a1 = 0.f;
#pragma unroll
    for (int d = 0; d < 32; ++d) {
      a0 = fmaf(h[d], ipw[j * 32 + d], a0);
      a1 = fmaf(h[d], ipw[(j + 64) * 32 + d], a1);
    }
    xm[(size_t)b * 65536 + j * L + l] = f2b(a0);
    z [(size_t)b * 65536 + j * L + l] = f2b(a1);
  }
}

// ---- k_mid: depthwise conv1d + SiLU + x_proj + dt(softplus) ----
__global__ __launch_bounds__(256) void k_mid(
    const bf* __restrict__ xm, const float* __restrict__ c1w,
    const float* __restrict__ c1b, const float* __restrict__ xpw,
    const float* __restrict__ dtw, const float* __restrict__ dtbp,
    bf* __restrict__ u, bf* __restrict__ dt_o,
    bf* __restrict__ Bt, bf* __restrict__ Ct) {
  int tid = blockIdx.x * 256 + threadIdx.x;   // (b,l)
  int l = tid & (L - 1);
  int b = tid >> 10;
  float um[64];
#pragma unroll
  for (int d = 0; d < 64; ++d) {
    float acc = c1b[d];
#pragma unroll
    for (int k = 0; k < 4; ++k) {
      int ls = l - 3 + k;
      float v = (ls >= 0) ? b2f(xm[(size_t)b * 65536 + d * L + ls]) : 0.f;
      acc = fmaf(c1w[d * 4 + k], v, acc);
    }
    float s = acc / (1.f + __expf(-acc));
    um[d] = s;
    u[(size_t)b * 65536 + d * L + l] = f2b(s);
  }
  float xd[34];
  for (int k = 0; k < 34; ++k) {
    float acc = 0.f;
#pragma unroll
    for (int d = 0; d < 64; ++d) acc = fmaf(um[d], xpw[k * 64 + d], acc);
    xd[k] = acc;
  }
#pragma unroll
  for (int d = 0; d < 64; ++d) {
    float raw = fmaf(xd[0], dtw[d * 2], fmaf(xd[1], dtw[d * 2 + 1], dtbp[d]));
    float sp = fmaxf(raw, 0.f) + log1pf(__expf(-fabsf(raw)));
    dt_o[(size_t)b * 65536 + d * L + l] = f2b(sp);
  }
#pragma unroll
  for (int n2 = 0; n2 < 16; ++n2) {
    Bt[(size_t)b * 16384 + l * 16 + n2] = f2b(xd[2 + n2]);
    Ct[(size_t)b * 16384 + l * 16 + n2] = f2b(xd[18 + n2]);
  }
}

// ---- k_scan: chunked parallel scan, fused gate + pool ----
// 32-lane group per (b,d); lane c owns steps [c*32, c*32+32); 16 states in regs.
// Sweep A: local scan (h0=0) -> chunk map (O_n, P_n) with P = exp(A*sum_dt).
// Hillis-Steele compose over 32 lanes -> h_in per chunk (exact).
// Sweep B: scan from h_in, y = C.h, yd = (y + u*D)*silu(z), pooled += yd.
__global__ __launch_bounds__(256) void k_scan(
    const bf* __restrict__ u, const bf* __restrict__ dt,
    const bf* __restrict__ z, const bf* __restrict__ Bt,
    const bf* __restrict__ Ct, const float* __restrict__ A_log,
    const float* __restrict__ Dp, float* __restrict__ pooled64) {
  int tid = blockIdx.x * 256 + threadIdx.x;   // 131072 threads
  int c = tid & 31;            // chunk
  int g = tid >> 5;            // (b,d) group, 4096 total
  int d = g & 63;
  int b = g >> 6;
  float An[16];
#pragma unroll
  for (int n = 0; n < 16; ++n) An[n] = -__expf(A_log[d * 16 + n]);
  const bf* up  = u  + (size_t)g * L;   // b*65536 + d*1024 == g*1024
  const bf* dtp = dt + (size_t)g * L;
  const bf* zp  = z  + (size_t)g * L;
  const short8* Bp = (const short8*)(Bt + (size_t)b * 16384);
  const short8* Cp = (const short8*)(Ct + (size_t)b * 16384);

  // chunk-local dt/u as 4x short8 (64B each stream)
  short8 dt8[4], u8[4];
  const short8* dps = (const short8*)(dtp + c * 32);
  const short8* ups = (const short8*)(up + c * 32);
#pragma unroll
  for (int q = 0; q < 4; ++q) { dt8[q] = dps[q]; u8[q] = ups[q]; }

  float h[16];
#pragma unroll
  for (int n = 0; n < 16; ++n) h[n] = 0.f;
  float sumdt = 0.f;
  // ---- sweep A: local scan from 0 ----
#pragma unroll
  for (int i = 0; i < 32; ++i) {
    float dtv = bits2f(dt8[i >> 3][i & 7]);
    float uv  = bits2f(u8[i >> 3][i & 7]);
    int l = c * 32 + i;
    short8 b0 = Bp[l * 2], b1 = Bp[l * 2 + 1];
    float du = dtv * uv;
    sumdt += dtv;
#pragma unroll
    for (int n = 0; n < 16; ++n) {
      float a = __expf(dtv * An[n]);
      float Bv = bits2f((n < 8) ? b0[n & 7] : b1[n & 7]);
      h[n] = fmaf(a, h[n], du * Bv);
    }
  }
  float P[16];
#pragma unroll
  for (int n = 0; n < 16; ++n) P[n] = __expf(An[n] * sumdt);

  // ---- prefix compose across 32 chunks (h = O) ----
#pragma unroll
  for (int s = 1; s < 32; s <<= 1) {
    bool act = (c >= s);
#pragma unroll
    for (int n = 0; n < 16; ++n) {
      float Po = __shfl_up(P[n], (unsigned)s, 32);
      float Oo = __shfl_up(h[n], (unsigned)s, 32);
      if (act) { h[n] = fmaf(P[n], Oo, h[n]); P[n] *= Po; }
    }
  }
  // exclusive prefix -> h_in
  float hin[16];
#pragma unroll
  for (int n = 0; n < 16; ++n) {
    float v = __shfl_up(h[n], 1u, 32);
    hin[n] = (c == 0) ? 0.f : v;
  }

  // ---- sweep B: true scan from h_in, gate + pool ----
  float Dd = Dp[d];
  short8 z8[4];
  const short8* zps = (const short8*)(zp + c * 32);
#pragma unroll
  for (int q = 0; q < 4; ++q) z8[q] = zps[q];
#pragma unroll
  for (int n = 0; n < 16; ++n) h[n] = hin[n];
  float pooled = 0.f;
#pragma unroll
  for (int i = 0; i < 32; ++i) {
    float dtv = bits2f(dt8[i >> 3][i & 7]);
    float uv  = bits2f(u8[i >> 3][i & 7]);
    float zv  = bits2f(z8[i >> 3][i & 7]);
    int l = c * 32 + i;
    short8 b0 = Bp[l * 2], b1 = Bp[l * 2 + 1];
    short8 c0 = Cp[l * 2], c1 = Cp[l * 2 + 1];
    float du = dtv * uv;
    float y0 = 0.f, y1 = 0.f, y2 = 0.f, y3 = 0.f;
#pragma unroll
    for (int n = 0; n < 16; ++n) {
      float a = __expf(dtv * An[n]);
      float Bv = bits2f((n < 8) ? b0[n & 7] : b1[n & 7]);
      h[n] = fmaf(a, h[n], du * Bv);
      float Cv = bits2f((n < 8) ? c0[n & 7] : c1[n & 7]);
      if ((n & 3) == 0)      y0 = fmaf(h[n], Cv, y0);
      else if ((n & 3) == 1) y1 = fmaf(h[n], Cv, y1);
      else if ((n & 3) == 2) y2 = fmaf(h[n], Cv, y2);
      else                   y3 = fmaf(h[n], Cv, y3);
    }
    float y = (y0 + y1) + (y2 + y3);
    float yd = fmaf(uv, Dd, y) * (zv / (1.f + __expf(-zv)));
    pooled += yd;
  }
  // reduce pooled across the 32-lane group
#pragma unroll
  for (int s = 1; s < 32; s <<= 1) pooled += __shfl_xor(pooled, s, 32);
  if (c == 0) pooled64[g] = pooled;
}

// ---- k_fc: out_proj(mean) + fc (out_proj commutes with mean-pool) ----
__global__ __launch_bounds__(128) void k_fc(
    const float* __restrict__ pooled64, const float* __restrict__ opw,
    const float* __restrict__ fcw, const float* __restrict__ fcb,
    float* __restrict__ out) {
  __shared__ float p64[64];
  __shared__ float o32[32];
  int b = blockIdx.x, t = threadIdx.x;
  if (t < 64) p64[t] = pooled64[b * 64 + t];
  __syncthreads();
  if (t < 32) {
    float s = 0.f;
#pragma unroll
    for (int d0 = 0; d0 < 64; ++d0) s = fmaf(p64[d0], opw[t * 64 + d0], s);
    o32[t] = s * (1.f / 1024.f);
  }
  __syncthreads();
  float acc = fcb[t];
#pragma unroll
  for (int j = 0; j < 32; ++j) acc = fmaf(o32[j], fcw[t * 32 + j], acc);
  out[b * 128 + t] = acc;
}

extern "C" void kernel_launch(void* const* d_in, const int* in_sizes, int n_in,
                              void* d_out, int out_size, void* d_ws, size_t ws_size,
                              hipStream_t stream) {
  const float* x      = (const float*)d_in[0];
  const float* conv_w = (const float*)d_in[1];
  const float* conv_b = (const float*)d_in[2];
  const float* bn_g   = (const float*)d_in[3];
  const float* bn_b   = (const float*)d_in[4];
  const float* bn_m   = (const float*)d_in[5];
  const float* bn_v   = (const float*)d_in[6];
  const float* ipw    = (const float*)d_in[7];
  const float* c1w    = (const float*)d_in[8];
  const float* c1b    = (const float*)d_in[9];
  const float* xpw    = (const float*)d_in[10];
  const float* dtw    = (const float*)d_in[11];
  const float* dtbp   = (const float*)d_in[12];
  const float* A_log  = (const float*)d_in[13];
  const float* Dp     = (const float*)d_in[14];
  const float* opw    = (const float*)d_in[15];
  const float* fcw    = (const float*)d_in[16];
  const float* fcb    = (const float*)d_in[17];

  char* ws = (char*)d_ws;
  bf* xmb = (bf*)(ws + 0);               // 8 MB
  bf* zb  = (bf*)(ws + 8388608);         // 8 MB
  bf* ub  = (bf*)(ws + 16777216);        // 8 MB
  bf* dtb = (bf*)(ws + 25165824);        // 8 MB
  bf* Btb = (bf*)(ws + 33554432);        // 2 MB
  bf* Ctb = (bf*)(ws + 35651584);        // 2 MB
  float* pooled = (float*)(ws + 37748736); // 16 KB

  hipLaunchKernelGGL(k_front, dim3(256), dim3(256), 0, stream,
                     x, conv_w, conv_b, bn_g, bn_b, bn_m, bn_v, ipw, xmb, zb);
  hipLaunchKernelGGL(k_mid, dim3(256), dim3(256), 0, stream,
                     xmb, c1w, c1b, xpw, dtw, dtbp, ub, dtb, Btb, Ctb);
  hipLaunchKernelGGL(k_scan, dim3(512), dim3(256), 0, stream,
                     ub, dtb, zb, Btb, Ctb, A_log, Dp, pooled);
  hipLaunchKernelGGL(k_fc, dim3(64), dim3(128), 0, stream,
                     pooled, opw, fcw, fcb, (float*)d_out);
}